// Round 2
// baseline (943.064 us; speedup 1.0000x reference)
//
#include <hip/hip_runtime.h>
#include <stdint.h>

// NNAKF: persistent-block fused Kalman+LSTM scan. ALL inputs/outputs are f32
// (reference is pure jnp.float32; round-1 NaN proved the bf16 read was wrong).
// 256 blocks x 256 threads (4 waves). Each block owns 4 batch rows for all 512 steps.
// W_hh / W_fc converted once to bf16 MFMA B-fragments (registers). h computed in
// f32, stored bf16 in LDS for the MFMA A-path. Kalman 4x4 P register-resident,
// 1 elem/lane (16 lanes/batch), cross-lane via __shfl; replicated per wave so
// only 2 __syncthreads per step.

#define DTc  0.1f
#define Q0V  0.01f      // PROCESS_NOISE_STD^2
#define RV   0.25f      // MEAS_NOISE_STD^2

typedef __bf16 bf16x8 __attribute__((ext_vector_type(8)));
typedef float  f32x4  __attribute__((ext_vector_type(4)));

__device__ __forceinline__ unsigned short f2bf(float f) {
    union { float f; unsigned int ui; } c; c.f = f;
    unsigned int u = c.ui;
    return (unsigned short)((u + 0x7FFFu + ((u >> 16) & 1u)) >> 16);   // RNE
}
__device__ __forceinline__ bf16x8 cvt8(float4 a, float4 b) {
    union { unsigned short us[8]; bf16x8 v; } r;
    r.us[0] = f2bf(a.x); r.us[1] = f2bf(a.y); r.us[2] = f2bf(a.z); r.us[3] = f2bf(a.w);
    r.us[4] = f2bf(b.x); r.us[5] = f2bf(b.y); r.us[6] = f2bf(b.z); r.us[7] = f2bf(b.w);
    return r.v;
}
__device__ __forceinline__ float sigmf(float x)  { return 1.0f / (1.0f + __expf(-x)); }
__device__ __forceinline__ float tanhf_(float x) { return 1.0f - 2.0f / (__expf(2.0f * x) + 1.0f); }

__global__ __launch_bounds__(256, 1) void nnakf_kernel(
    const float* __restrict__ meas,   // [1024][512][2] f32
    const float* __restrict__ Qt,     // [10][4][4]
    const float* __restrict__ Wih,    // [512][2]
    const float* __restrict__ Whh,    // [512][128]
    const float* __restrict__ bih,    // [512]
    const float* __restrict__ bhh,    // [512]
    const float* __restrict__ Wfc,    // [10][128]
    const float* __restrict__ bfc,    // [10]
    float* __restrict__ out)          // [1024][512][4] f32
{
    __shared__ float          meas_s[4 * 1024];      // f32 z pairs, [b][t*2+c]
    __shared__ float          gates_s[512 * 4];      // [n][b] pre-activations
    __shared__ unsigned short h_ext[4 * 160];        // h as bf16, row stride 160 (320B)
    __shared__ float2         wih_s[512];            // W_ih[n][0..1] f32
    __shared__ float          qt_s[160];             // Q_tilde f32 [10][16]
    __shared__ float          in_s[8];               // In[b][0..1]
    __shared__ float          sigma_s[4 * 4 * 16];   // per-wave [w][b][n<16]

    const int tid  = threadIdx.x;
    const int w    = tid >> 6;         // wave id 0..3
    const int lane = tid & 63;
    const int idx  = lane & 15;        // MFMA row/col id
    const int q    = lane >> 4;        // MFMA quad == batch id for Kalman lanes
    const int i    = idx >> 2, j = idx & 3;
    const int base = lane & 48;        // first lane of this batch group
    const int bg0  = blockIdx.x * 4;

    // ---- one-time init ----
    {
        const float4* g4 = (const float4*)(meas + (size_t)bg0 * 1024);
        float4* ms4 = (float4*)meas_s;
        for (int k = tid; k < 1024; k += 256) ms4[k] = g4[k];
        const float4* wi4 = (const float4*)Wih;
        float4* ws4 = (float4*)wih_s;
        for (int k = tid; k < 256; k += 256) ws4[k] = wi4[k];
        for (int k = tid; k < 160; k += 256) qt_s[k] = Qt[k];
        for (int k = tid; k < 640; k += 256) h_ext[k] = 0;
    }

    // register-resident weight fragments (bf16, RNE from f32)
    bf16x8 wf[8][4];   // 8 n-tiles x 4 k-steps
    float  breg[8];    // b_ih + b_hh for this lane's column per tile
    const float4* whh4 = (const float4*)Whh;
    #pragma unroll
    for (int t8 = 0; t8 < 8; ++t8) {
        const int nb = ((t8 >> 1) << 7) + (w << 5) + ((t8 & 1) << 4);
        const int n  = nb + idx;
        breg[t8] = bih[n] + bhh[n];
        #pragma unroll
        for (int s = 0; s < 4; ++s) {
            float4 u0 = whh4[n * 32 + s * 8 + q * 2];
            float4 u1 = whh4[n * 32 + s * 8 + q * 2 + 1];
            wf[t8][s] = cvt8(u0, u1);   // B[k = s*32+q*8+j][n]
        }
    }
    bf16x8 fcf[4];
    #pragma unroll
    for (int s = 0; s < 4; ++s) {
        float4 u0 = make_float4(0.f, 0.f, 0.f, 0.f), u1 = u0;
        if (idx < 10) {
            u0 = ((const float4*)Wfc)[idx * 32 + s * 8 + q * 2];
            u1 = ((const float4*)Wfc)[idx * 32 + s * 8 + q * 2 + 1];
        }
        fcf[s] = cvt8(u0, u1);
    }
    const float bfc_r = (idx < 10) ? bfc[idx] : 0.0f;

    // persistent per-lane state (replicated per wave)
    float P_reg = (i == j) ? 1.0f : 0.0f;   // P[b][i][j]
    float xn = 0.0f;                        // x[b][i] (same across j)
    float c0 = 0.0f, c1 = 0.0f;             // LSTM cell state (phase-B mapping)
    float Pp0 = 0.f, xp = 0.f, in0 = 0.f, in1 = 0.f;

    __syncthreads();

    for (int t = 0; t < 512; ++t) {
        // ================= Phase A: predict + recurrent GEMM =================
        {
            const float z0 = meas_s[q * 1024 + 2 * t];
            const float z1 = meas_s[q * 1024 + 2 * t + 1];
            // P_pred0 = F P F^T + Q0 (elementwise over lanes via shuffles)
            const float pi2j  = __shfl(P_reg, base + ((((i + 2) & 3)) << 2) + j, 64);
            const float pij2  = __shfl(P_reg, base + (i << 2) + ((j + 2) & 3), 64);
            const float pi2j2 = __shfl(P_reg, base + ((((i + 2) & 3)) << 2) + ((j + 2) & 3), 64);
            float pp = P_reg;
            if (i < 2) pp += DTc * pi2j;
            if (j < 2) pp += DTc * pij2;
            if (i < 2 && j < 2) pp += DTc * DTc * pi2j2;
            if (i == j) pp += Q0V;
            Pp0 = pp;
            const float xi2 = __shfl(xn, base + ((((i + 2) & 3)) << 2), 64);
            xp = xn + ((i < 2) ? DTc * xi2 : 0.0f);
            const float xp0 = __shfl(xp, base + 0, 64);
            const float xp1 = __shfl(xp, base + 4, 64);
            in0 = z0 - xp0;
            in1 = z1 - xp1;
            const float pp00 = __shfl(Pp0, base + 0, 64);
            const float pp11 = __shfl(Pp0, base + 5, 64);
            const float In0 = in0 * in0 / (pp00 + RV);
            const float In1 = in1 * in1 / (pp11 + RV);
            if (w == 0 && idx == 0) { in_s[q * 2] = In0; in_s[q * 2 + 1] = In1; }
        }
        // recurrent GEMM: gates_pre[b][n] = sum_k h[b][k] * W_hh[n][k]
        {
            f32x4 acc[8];
            #pragma unroll
            for (int t8 = 0; t8 < 8; ++t8) acc[t8] = (f32x4){0.f, 0.f, 0.f, 0.f};
            bf16x8 af[4];
            #pragma unroll
            for (int s = 0; s < 4; ++s) {
                uint4 u = *(const uint4*)&h_ext[(idx & 3) * 160 + s * 32 + q * 8];
                af[s] = __builtin_bit_cast(bf16x8, u);   // A[m=idx&3][k=s*32+q*8+j]
            }
            #pragma unroll
            for (int s = 0; s < 4; ++s)
                #pragma unroll
                for (int t8 = 0; t8 < 8; ++t8)
                    acc[t8] = __builtin_amdgcn_mfma_f32_16x16x32_bf16(af[s], wf[t8][s], acc[t8], 0, 0, 0);
            if (lane < 16) {
                #pragma unroll
                for (int t8 = 0; t8 < 8; ++t8) {
                    const int nb = ((t8 >> 1) << 7) + (w << 5) + ((t8 & 1) << 4);
                    f32x4 v = acc[t8];
                    v[0] += breg[t8]; v[1] += breg[t8]; v[2] += breg[t8]; v[3] += breg[t8];
                    *(f32x4*)&gates_s[(nb + lane) * 4] = v;   // [n][b]
                }
            }
        }
        __syncthreads();   // B1: gates + In visible

        // ================= Phase B: LSTM pointwise (all 256 threads) =========
        {
            const int bb = tid & 3;
            const float In0b = in_s[bb * 2], In1b = in_s[bb * 2 + 1];
            #pragma unroll
            for (int u2 = 0; u2 < 2; ++u2) {
                const int h = (tid >> 2) + u2 * 64;
                float pre[4];
                #pragma unroll
                for (int g = 0; g < 4; ++g) {
                    const float2 wp = wih_s[g * 128 + h];
                    pre[g] = gates_s[(g * 128 + h) * 4 + bb] + In0b * wp.x + In1b * wp.y;
                }
                const float cprev = u2 ? c1 : c0;
                const float cn = sigmf(pre[1]) * cprev + sigmf(pre[0]) * tanhf_(pre[2]);
                const float hn = sigmf(pre[3]) * tanhf_(cn);
                if (u2) c1 = cn; else c0 = cn;
                h_ext[bb * 160 + h] = f2bf(hn);
            }
        }
        __syncthreads();   // B2: new h visible

        // ============ Phase C: fc GEMM + sigma + Kalman update (per wave) ====
        {
            f32x4 facc = (f32x4){0.f, 0.f, 0.f, 0.f};
            #pragma unroll
            for (int s = 0; s < 4; ++s) {
                uint4 u = *(const uint4*)&h_ext[(idx & 3) * 160 + s * 32 + q * 8];
                bf16x8 a2 = __builtin_bit_cast(bf16x8, u);
                facc = __builtin_amdgcn_mfma_f32_16x16x32_bf16(a2, fcf[s], facc, 0, 0, 0);
            }
            if (lane < 10) {   // facc[r] = sigma_pre[batch r][n=lane], any q
                #pragma unroll
                for (int r = 0; r < 4; ++r)
                    sigma_s[(w * 4 + r) * 16 + lane] = sigmf(facc[r] + bfc_r);
            }
            // same-wave LDS write->read: DS ops from one wave process in order
            float Pp = Pp0;
            #pragma unroll
            for (int n = 0; n < 10; ++n)
                Pp += sigma_s[(w * 4 + q) * 16 + n] * qt_s[n * 16 + idx];
            const float s00 = __shfl(Pp, base + 0, 64) + RV;
            const float s01 = __shfl(Pp, base + 1, 64);
            const float s10 = __shfl(Pp, base + 4, 64);
            const float s11 = __shfl(Pp, base + 5, 64) + RV;
            const float pi0 = __shfl(Pp, base + (i << 2), 64);
            const float pi1 = __shfl(Pp, base + (i << 2) + 1, 64);
            const float p0j = __shfl(Pp, base + j, 64);
            const float p1j = __shfl(Pp, base + 4 + j, 64);
            const float det  = s00 * s11 - s01 * s10;
            const float rdet = 1.0f / det;
            const float Ki0 = (pi0 * s11 - pi1 * s10) * rdet;
            const float Ki1 = (pi1 * s00 - pi0 * s01) * rdet;
            xn    = xp + Ki0 * in0 + Ki1 * in1;
            P_reg = Pp - (Ki0 * p0j + Ki1 * p1j);
            if (w == 0) {
                const float x1 = __shfl(xn, base + 4, 64);
                const float x2 = __shfl(xn, base + 8, 64);
                const float x3 = __shfl(xn, base + 12, 64);
                if (idx == 0) {
                    float4* o = (float4*)out;
                    o[(size_t)(bg0 + q) * 512 + t] = make_float4(xn, x1, x2, x3);
                }
            }
        }
        // no barrier needed here: next Phase A only reads h_ext (B2-protected)
        // and writes gates_s/in_s, whose Phase-B readers finished before B2.
    }
}

extern "C" void kernel_launch(void* const* d_in, const int* in_sizes, int n_in,
                              void* d_out, int out_size, void* d_ws, size_t ws_size,
                              hipStream_t stream) {
    (void)in_sizes; (void)n_in; (void)out_size; (void)d_ws; (void)ws_size;
    nnakf_kernel<<<256, 256, 0, stream>>>(
        (const float*)d_in[0],  // measurements
        (const float*)d_in[1],  // Q_tilde
        (const float*)d_in[2],  // W_ih
        (const float*)d_in[3],  // W_hh
        (const float*)d_in[4],  // b_ih
        (const float*)d_in[5],  // b_hh
        (const float*)d_in[6],  // W_fc
        (const float*)d_in[7],  // b_fc
        (float*)d_out);
}